// Round 6
// baseline (1074.430 us; speedup 1.0000x reference)
//
#include <hip/hip_runtime.h>
#include <math.h>

#define D 128
#define SCAN_B 256   // elements per scan block

typedef __attribute__((ext_vector_type(8))) short bfrag;   // 8 bf16 (4 VGPRs)
typedef __attribute__((ext_vector_type(4))) float ffrag;   // 4 fp32 acc

__device__ inline unsigned short f2bf(float f) {           // RNE fp32->bf16
    unsigned u = __float_as_uint(f);
    u += 0x7FFF + ((u >> 16) & 1);
    return (unsigned short)(u >> 16);
}
__device__ inline float bf2f(unsigned short h) {
    return __uint_as_float(((unsigned)h) << 16);
}
__device__ inline unsigned pack_bf2(float a, float b) {    // [lo=a, hi=b]
    return ((unsigned)f2bf(a)) | (((unsigned)f2bf(b)) << 16);
}

// ---------------- fused init: wsplit W1/W2 + gather h0 + zero deg ----------------
__global__ void init_kernel(const float* __restrict__ emb,
                            const int* __restrict__ ids,
                            uint4* __restrict__ h4,
                            const float* __restrict__ W1,
                            const float* __restrict__ W2,
                            unsigned short* __restrict__ hi1,
                            unsigned short* __restrict__ lo1,
                            unsigned short* __restrict__ hi2,
                            unsigned short* __restrict__ lo2,
                            int* __restrict__ deg,
                            int n_nodes, int np1) {
    int idx = blockIdx.x * blockDim.x + threadIdx.x;
    // gather: one thread = 8 dims (two float4 reads -> one uint4 bf16 write)
    if (idx < n_nodes * 16) {
        int node = idx >> 4;
        int c = idx & 15;
        size_t cid = (size_t)ids[node];
        const float4* s = (const float4*)(emb + cid * D) + c * 2;
        float4 v0 = s[0];
        float4 v1 = s[1];
        uint4 p;
        p.x = pack_bf2(v0.x, v0.y);
        p.y = pack_bf2(v0.z, v0.w);
        p.z = pack_bf2(v1.x, v1.y);
        p.w = pack_bf2(v1.z, v1.w);
        h4[(size_t)node * 16 + c] = p;
    }
    if (idx < D * D) {
        float f1 = W1[idx];
        unsigned short h1 = f2bf(f1);
        hi1[idx] = h1;
        lo1[idx] = f2bf(f1 - bf2f(h1));
        float f2 = W2[idx];
        unsigned short h2 = f2bf(f2);
        hi2[idx] = h2;
        lo2[idx] = f2bf(f2 - bf2f(h2));
    }
    if (idx < np1) deg[idx] = 0;
}

// ---------------- CSR build ----------------
__global__ void degree_kernel(const int* __restrict__ dst,
                              int* __restrict__ deg, int n_edges) {
    int e = blockIdx.x * blockDim.x + threadIdx.x;
    if (e < n_edges) atomicAdd(&deg[dst[e]], 1);
}

__global__ __launch_bounds__(SCAN_B) void scan_block_kernel(
        const int* __restrict__ deg, int* __restrict__ row_ptr,
        int* __restrict__ blocksums, int n) {
    __shared__ int s[SCAN_B];
    int i = blockIdx.x * SCAN_B + threadIdx.x;
    int v = (i < n) ? deg[i] : 0;
    s[threadIdx.x] = v;
    __syncthreads();
    #pragma unroll
    for (int off = 1; off < SCAN_B; off <<= 1) {
        int t = (threadIdx.x >= off) ? s[threadIdx.x - off] : 0;
        __syncthreads();
        s[threadIdx.x] += t;
        __syncthreads();
    }
    if (i < n) row_ptr[i] = s[threadIdx.x] - v;      // exclusive
    if (threadIdx.x == SCAN_B - 1) blocksums[blockIdx.x] = s[SCAN_B - 1];
}

__global__ __launch_bounds__(512) void scan_sums_kernel(int* __restrict__ blocksums,
                                                        int nb) {
    __shared__ int s[512];
    int v = (threadIdx.x < nb) ? blocksums[threadIdx.x] : 0;
    s[threadIdx.x] = v;
    __syncthreads();
    #pragma unroll
    for (int off = 1; off < 512; off <<= 1) {
        int t = (threadIdx.x >= off) ? s[threadIdx.x - off] : 0;
        __syncthreads();
        s[threadIdx.x] += t;
        __syncthreads();
    }
    if (threadIdx.x < nb) blocksums[threadIdx.x] = s[threadIdx.x] - v;  // exclusive
}

__global__ void add_offsets_kernel(int* __restrict__ row_ptr,
                                   const int* __restrict__ blocksums,
                                   int* __restrict__ cursor, int n, int n_nodes) {
    int i = blockIdx.x * blockDim.x + threadIdx.x;
    if (i >= n) return;
    int rp = row_ptr[i] + blocksums[i / SCAN_B];
    row_ptr[i] = rp;
    if (i < n_nodes) cursor[i] = rp;
}

__global__ void csr_fill_kernel(const int* __restrict__ src,
                                const int* __restrict__ dst,
                                int* __restrict__ cursor,
                                int* __restrict__ esrc, int n_edges) {
    int e = blockIdx.x * blockDim.x + threadIdx.x;
    if (e >= n_edges) return;
    int pos = atomicAdd(&cursor[dst[e]], 1);
    esrc[pos] = src[e];
}

// ---------------- fused GCN layer: y = relu(Agg(h) @ W^T + b) ----------------
// One wave per 16-node group. Agg phase: 4 passes x 4 nodes (one node per
// 16-lane group, lane owns a uint4 = 8 dims); rows packed bf16 into
// wave-private LDS with 272B row stride (pad 16B -> 2-way banks = free).
// MFMA phase: A-frags straight from LDS (ds_read_b128), B from Whi/Wlo
// (64KB, L1-hot). C = A*Whi + A*Wlo. Epilogue: relu+bias -> y, or fused
// sigmoid head -> out.
__global__ __launch_bounds__(256) void gcn_layer_kernel(
        const uint4* __restrict__ h4,
        const int* __restrict__ row_ptr,
        const int* __restrict__ esrc,
        const unsigned short* __restrict__ Whi,
        const unsigned short* __restrict__ Wlo,
        const float* __restrict__ b,
        unsigned short* __restrict__ y,
        const float* __restrict__ wout,
        const float* __restrict__ bout,
        float* __restrict__ outp,
        int n_nodes, int fuse_out) {
    __shared__ unsigned short lds[4][16 * 136];   // 4 waves x 16 rows x 272B
    const int wv   = threadIdx.x >> 6;
    const int lane = threadIdx.x & 63;
    const int c    = lane & 15;      // chunk / col index
    const int gid  = lane >> 4;      // group / quad index
    const int wave = blockIdx.x * 4 + wv;
    const int nwaves = gridDim.x * 4;
    const int ngroups = (n_nodes + 15) >> 4;
    const int iters = (ngroups + nwaves - 1) / nwaves;

    float bvals[8], wvals[8];
    #pragma unroll
    for (int nt = 0; nt < 8; ++nt) {
        bvals[nt] = b[nt * 16 + c];
        wvals[nt] = fuse_out ? wout[nt * 16 + c] : 0.f;
    }
    const float bout0 = fuse_out ? bout[0] : 0.f;

    for (int it = 0; it < iters; ++it) {
        int g = wave + it * nwaves;
        bool active = g < ngroups;

        // ---- aggregation: 4 passes, node = g*16 + pass*4 + gid ----
        #pragma unroll
        for (int pass = 0; pass < 4; ++pass) {
            int node = g * 16 + pass * 4 + gid;
            int beg = 0, end = 0;
            if (active && node < n_nodes) {
                beg = row_ptr[node];
                end = row_ptr[node + 1];
            }
            float a0 = 0.f, a1 = 0.f, a2 = 0.f, a3 = 0.f;
            float a4 = 0.f, a5 = 0.f, a6 = 0.f, a7 = 0.f;
            int i = beg;
            for (; i + 1 < end; i += 2) {
                int s0 = esrc[i];
                int s1 = esrc[i + 1];
                uint4 u0 = h4[(size_t)s0 * 16 + c];
                uint4 u1 = h4[(size_t)s1 * 16 + c];
                a0 += __uint_as_float(u0.x << 16) + __uint_as_float(u1.x << 16);
                a1 += __uint_as_float(u0.x & 0xffff0000u) + __uint_as_float(u1.x & 0xffff0000u);
                a2 += __uint_as_float(u0.y << 16) + __uint_as_float(u1.y << 16);
                a3 += __uint_as_float(u0.y & 0xffff0000u) + __uint_as_float(u1.y & 0xffff0000u);
                a4 += __uint_as_float(u0.z << 16) + __uint_as_float(u1.z << 16);
                a5 += __uint_as_float(u0.z & 0xffff0000u) + __uint_as_float(u1.z & 0xffff0000u);
                a6 += __uint_as_float(u0.w << 16) + __uint_as_float(u1.w << 16);
                a7 += __uint_as_float(u0.w & 0xffff0000u) + __uint_as_float(u1.w & 0xffff0000u);
            }
            if (i < end) {
                uint4 u = h4[(size_t)esrc[i] * 16 + c];
                a0 += __uint_as_float(u.x << 16);
                a1 += __uint_as_float(u.x & 0xffff0000u);
                a2 += __uint_as_float(u.y << 16);
                a3 += __uint_as_float(u.y & 0xffff0000u);
                a4 += __uint_as_float(u.z << 16);
                a5 += __uint_as_float(u.z & 0xffff0000u);
                a6 += __uint_as_float(u.w << 16);
                a7 += __uint_as_float(u.w & 0xffff0000u);
            }
            int m = pass * 4 + gid;
            uint4 p;
            p.x = pack_bf2(a0, a1);
            p.y = pack_bf2(a2, a3);
            p.z = pack_bf2(a4, a5);
            p.w = pack_bf2(a6, a7);
            *(uint4*)&lds[wv][m * 136 + c * 8] = p;
        }
        __syncthreads();

        // ---- MFMA: A-frag lane holds X[m=c][k=kt*32+gid*8 .. +7] ----
        bfrag a[4];
        #pragma unroll
        for (int kt = 0; kt < 4; ++kt)
            a[kt] = *(const bfrag*)&lds[wv][c * 136 + kt * 32 + gid * 8];

        const size_t bbase = (size_t)c * D + gid * 8;
        float part0 = 0.f, part1 = 0.f, part2 = 0.f, part3 = 0.f;

        #pragma unroll
        for (int nt = 0; nt < 8; ++nt) {
            ffrag cc = {0.f, 0.f, 0.f, 0.f};
            #pragma unroll
            for (int kt = 0; kt < 4; ++kt) {
                size_t off = (size_t)nt * 16 * D + bbase + kt * 32;
                bfrag bh = *(const bfrag*)(Whi + off);
                bfrag bl = *(const bfrag*)(Wlo + off);
                cc = __builtin_amdgcn_mfma_f32_16x16x32_bf16(a[kt], bh, cc, 0, 0, 0);
                cc = __builtin_amdgcn_mfma_f32_16x16x32_bf16(a[kt], bl, cc, 0, 0, 0);
            }
            // C layout: value r is C[row = gid*4 + r][col = c]
            if (fuse_out) {
                part0 += fmaxf(cc[0] + bvals[nt], 0.f) * wvals[nt];
                part1 += fmaxf(cc[1] + bvals[nt], 0.f) * wvals[nt];
                part2 += fmaxf(cc[2] + bvals[nt], 0.f) * wvals[nt];
                part3 += fmaxf(cc[3] + bvals[nt], 0.f) * wvals[nt];
            } else if (active) {
                #pragma unroll
                for (int r = 0; r < 4; ++r) {
                    int onode = g * 16 + gid * 4 + r;
                    if (onode < n_nodes)
                        y[(size_t)onode * D + nt * 16 + c] =
                            f2bf(fmaxf(cc[r] + bvals[nt], 0.f));
                }
            }
        }

        if (fuse_out && active) {
            float part[4] = {part0, part1, part2, part3};
            #pragma unroll
            for (int r = 0; r < 4; ++r) {
                float s = part[r];
                s += __shfl_xor(s, 1, 64);
                s += __shfl_xor(s, 2, 64);
                s += __shfl_xor(s, 4, 64);
                s += __shfl_xor(s, 8, 64);   // reduce over 16 cols within quad
                int onode = g * 16 + gid * 4 + r;
                if (c == 0 && onode < n_nodes)
                    outp[onode] = 1.0f / (1.0f + expf(-(s + bout0)));
            }
        }
        __syncthreads();   // protect LDS before next iteration's writes
    }
}

extern "C" void kernel_launch(void* const* d_in, const int* in_sizes, int n_in,
                              void* d_out, int out_size, void* d_ws, size_t ws_size,
                              hipStream_t stream) {
    const int*   cncpt_ids = (const int*)d_in[0];
    const int*   src       = (const int*)d_in[1];
    const int*   dst       = (const int*)d_in[2];
    const float* emb       = (const float*)d_in[3];
    const float* W1        = (const float*)d_in[4];
    const float* b1        = (const float*)d_in[5];
    const float* W2        = (const float*)d_in[6];
    const float* b2        = (const float*)d_in[7];
    const float* Wout      = (const float*)d_in[8];
    const float* bout      = (const float*)d_in[9];
    float* out = (float*)d_out;

    const int n_nodes = in_sizes[0];
    const int n_edges = in_sizes[1];

    // ---- workspace carve-up ----
    unsigned short* bufA = (unsigned short*)d_ws;          // N*D bf16 (h0 / h1 in)
    unsigned short* bufB = bufA + (size_t)n_nodes * D;     // N*D bf16 (h1 out)
    int*   deg      = (int*)(bufB + (size_t)n_nodes * D);  // N+1 ints
    int*   row_ptr  = deg + (n_nodes + 1);                 // N+1 ints
    int*   cursor   = row_ptr + (n_nodes + 1);             // N ints
    int*   blocksums= cursor + n_nodes;                    // 512 ints
    int*   esrc     = blocksums + 512;                     // E ints
    unsigned short* W1hi = (unsigned short*)(esrc + n_edges);  // D*D each
    unsigned short* W1lo = W1hi + D * D;
    unsigned short* W2hi = W1lo + D * D;
    unsigned short* W2lo = W2hi + D * D;

    const int np1 = n_nodes + 1;
    const int nb_scan = (np1 + SCAN_B - 1) / SCAN_B;  // <= 512

    // ---- fused init: wsplit + gather + zero deg ----
    init_kernel<<<(n_nodes * 16 + 255) / 256, 256, 0, stream>>>(
        emb, cncpt_ids, (uint4*)bufA, W1, W2,
        W1hi, W1lo, W2hi, W2lo, deg, n_nodes, np1);

    // ---- CSR build ----
    degree_kernel<<<(n_edges + 255) / 256, 256, 0, stream>>>(dst, deg, n_edges);
    scan_block_kernel<<<nb_scan, SCAN_B, 0, stream>>>(deg, row_ptr, blocksums, np1);
    scan_sums_kernel<<<1, 512, 0, stream>>>(blocksums, nb_scan);
    add_offsets_kernel<<<(np1 + 255) / 256, 256, 0, stream>>>(
        row_ptr, blocksums, cursor, np1, n_nodes);
    csr_fill_kernel<<<(n_edges + 255) / 256, 256, 0, stream>>>(
        src, dst, cursor, esrc, n_edges);

    const int ngroups = (n_nodes + 15) / 16;
    const int layer_grid = (ngroups + 3) / 4;   // one wave per 16-node group

    // ---- layer 1 (fused agg + linear) ----
    gcn_layer_kernel<<<layer_grid, 256, 0, stream>>>(
        (const uint4*)bufA, row_ptr, esrc, W1hi, W1lo, b1,
        bufB, nullptr, nullptr, nullptr, n_nodes, 0);

    // ---- layer 2 (fused agg + linear + sigmoid head) ----
    gcn_layer_kernel<<<layer_grid, 256, 0, stream>>>(
        (const uint4*)bufB, row_ptr, esrc, W2hi, W2lo, b2,
        nullptr, Wout, bout, out, n_nodes, 1);
}